// Round 5
// baseline (384.378 us; speedup 1.0000x reference)
//
#include <hip/hip_runtime.h>
#include <math.h>

#define NHEAD 8
#define DD 128
#define HIDD 512

typedef _Float16 half8 __attribute__((ext_vector_type(8)));
typedef float floatx4 __attribute__((ext_vector_type(4)));

// XOR-swizzle (T2): spreads 16B chunks of different rows across bank quads.
__device__ __forceinline__ int swz256(int row, int bytecol) {  // 256B rows (128 f16)
  return row * 256 + (bytecol ^ ((row & 7) << 4));
}
__device__ __forceinline__ int swz512(int row, int bytecol) {  // 512B rows (128 f32)
  return row * 512 + (bytecol ^ ((row & 7) << 4));
}

// ---------------- K0: pack weights to f16, fragment-contiguous ----------------
// Layout [kc][col][l4][i8]: a wave's B-frag load (l15->col, l4->k-chunk) is 1KB contiguous.
__global__ __launch_bounds__(256) void pack_kernel(
    const float* __restrict__ W, const float* __restrict__ W1,
    const float* __restrict__ W2, _Float16* __restrict__ WP,
    _Float16* __restrict__ W1P, _Float16* __restrict__ W2P)
{
  int i = blockIdx.x * 256 + threadIdx.x;
  if (i < 4 * 128 * 4 * 8) {   // WP <- W[128][128]
    int ii = i & 7, l4 = (i >> 3) & 3, col = (i >> 5) & 127, kc = i >> 12;
    WP[i] = (_Float16)W[(kc * 32 + l4 * 8 + ii) * DD + col];
  }
  if (i < 4 * 512 * 4 * 8) {   // W1P <- W1[128][512]
    int ii = i & 7, l4 = (i >> 3) & 3, col = (i >> 5) & 511, kc = i >> 14;
    W1P[i] = (_Float16)W1[(kc * 32 + l4 * 8 + ii) * HIDD + col];
  }
  if (i < 16 * 128 * 4 * 8) {  // W2P <- W2[512][128]
    int ii = i & 7, l4 = (i >> 3) & 3, col = (i >> 5) & 127, kch = i >> 12;
    W2P[i] = (_Float16)W2[(kch * 32 + l4 * 8 + ii) * DD + col];
  }
}

// ---------------- K1: MFMA feat = f16(x @ W), el/er per (node, head). 32 rows/block ----------------
__global__ __launch_bounds__(256) void feat_mfma_kernel(
    const float* __restrict__ x, const _Float16* __restrict__ WP,
    const float* __restrict__ attn_l, const float* __restrict__ attn_r,
    _Float16* __restrict__ feat16, float* __restrict__ el, float* __restrict__ er, int N)
{
  __shared__ char xs[32 * 512];   // 16KB swizzled f32 A-tile
  const int tid = threadIdx.x;
  const int wv = tid >> 6, lane = tid & 63;
  const int l15 = lane & 15, l4 = lane >> 4;
  const int n0 = blockIdx.x * 32;

  {  // stage x: 8 threads/row, 4 x 16B each, coalesced global, swizzled LDS
    const int row = tid >> 3;
    const int seg = tid & 7;
    const bool ok = (n0 + row) < N;
    const float4* srcp = (const float4*)(x + (size_t)(n0 + row) * DD + seg * 16);
    const float4 z = make_float4(0.f, 0.f, 0.f, 0.f);
    #pragma unroll
    for (int c = 0; c < 4; ++c) {
      float4 v = ok ? srcp[c] : z;
      *(float4*)(xs + swz512(row, seg * 64 + c * 16)) = v;
    }
  }
  __syncthreads();

  floatx4 acc[2][2];
  #pragma unroll
  for (int mf = 0; mf < 2; ++mf) { acc[mf][0] = (floatx4)0.f; acc[mf][1] = (floatx4)0.f; }

  #pragma unroll
  for (int kc = 0; kc < 4; ++kc) {
    half8 b0 = *(const half8*)(WP + ((kc * 128 + wv * 32 + l15) * 4 + l4) * 8);
    half8 b1 = *(const half8*)(WP + ((kc * 128 + wv * 32 + 16 + l15) * 4 + l4) * 8);
    #pragma unroll
    for (int mf = 0; mf < 2; ++mf) {
      const int row = mf * 16 + l15;
      float4 a0 = *(const float4*)(xs + swz512(row, kc * 128 + l4 * 32));
      float4 a1 = *(const float4*)(xs + swz512(row, kc * 128 + l4 * 32 + 16));
      half8 af;
      af[0] = (_Float16)a0.x; af[1] = (_Float16)a0.y; af[2] = (_Float16)a0.z; af[3] = (_Float16)a0.w;
      af[4] = (_Float16)a1.x; af[5] = (_Float16)a1.y; af[6] = (_Float16)a1.z; af[7] = (_Float16)a1.w;
      acc[mf][0] = __builtin_amdgcn_mfma_f32_16x16x32_f16(af, b0, acc[mf][0], 0, 0, 0);
      acc[mf][1] = __builtin_amdgcn_mfma_f32_16x16x32_f16(af, b1, acc[mf][1], 0, 0, 0);
    }
  }

  // epilogue: store feat16; el/er = 16-lane shfl reduction per row/head
  const float al0 = attn_l[wv * 32 + l15], al1 = attn_l[wv * 32 + 16 + l15];
  const float ar0 = attn_r[wv * 32 + l15], ar1 = attn_r[wv * 32 + 16 + l15];
  #pragma unroll
  for (int mf = 0; mf < 2; ++mf) {
    #pragma unroll
    for (int r = 0; r < 4; ++r) {
      const int row = n0 + mf * 16 + l4 * 4 + r;
      float v0 = acc[mf][0][r], v1 = acc[mf][1][r];
      float e0l = v0 * al0, e0r = v0 * ar0;
      float e1l = v1 * al1, e1r = v1 * ar1;
      #pragma unroll
      for (int d = 1; d < 16; d <<= 1) {
        e0l += __shfl_xor(e0l, d, 64); e0r += __shfl_xor(e0r, d, 64);
        e1l += __shfl_xor(e1l, d, 64); e1r += __shfl_xor(e1r, d, 64);
      }
      if (row < N) {
        feat16[(size_t)row * DD + wv * 32 + l15] = (_Float16)v0;
        feat16[(size_t)row * DD + wv * 32 + 16 + l15] = (_Float16)v1;
        if (l15 == 0) {
          el[row * NHEAD + wv * 2] = e0l;     er[row * NHEAD + wv * 2] = e0r;
          el[row * NHEAD + wv * 2 + 1] = e1l; er[row * NHEAD + wv * 2 + 1] = e1r;
        }
      }
    }
  }
}

// ---------------- K2: in-degree histogram ----------------
__global__ __launch_bounds__(256) void count_kernel(const int* __restrict__ dst,
                                                    int* __restrict__ counts, int E)
{
  int e = blockIdx.x * 256 + threadIdx.x;
  if (e < E) atomicAdd(&counts[dst[e]], 1);
}

// ---------------- K3a: per-1024-chunk local exclusive scan + chunk totals ----------------
__global__ __launch_bounds__(256) void scan1_kernel(const int* __restrict__ counts,
                                                    int* __restrict__ offsets,
                                                    int* __restrict__ btot)
{
  __shared__ int wsum[4];
  const int lane = threadIdx.x & 63;
  const int wid = threadIdx.x >> 6;
  int4 c = *(const int4*)(counts + blockIdx.x * 1024 + threadIdx.x * 4);
  int q = c.x + c.y + c.z + c.w;
  int incl = q;
  #pragma unroll
  for (int d = 1; d < 64; d <<= 1) {
    int t = __shfl_up(incl, d, 64);
    if (lane >= d) incl += t;
  }
  if (lane == 63) wsum[wid] = incl;
  __syncthreads();
  int wprefix = 0;
  for (int w = 0; w < wid; ++w) wprefix += wsum[w];
  int excl = wprefix + incl - q;
  int4 o;
  o.x = excl; o.y = excl + c.x; o.z = o.y + c.y; o.w = o.z + c.z;
  *(int4*)(offsets + blockIdx.x * 1024 + threadIdx.x * 4) = o;
  if (threadIdx.x == 0) btot[blockIdx.x] = wsum[0] + wsum[1] + wsum[2] + wsum[3];
}

// ---------------- K3b: exclusive scan of chunk totals (1 wave) ----------------
__global__ __launch_bounds__(64) void scan2_kernel(const int* __restrict__ btot,
                                                   int* __restrict__ bof, int nchunk)
{
  const int t = threadIdx.x;
  const int K = (nchunk + 63) >> 6;
  const int base = t * K;
  int s = 0;
  for (int i = 0; i < K; ++i) if (base + i < nchunk) s += btot[base + i];
  int incl = s;
  #pragma unroll
  for (int d = 1; d < 64; d <<= 1) {
    int tt = __shfl_up(incl, d, 64);
    if (t >= d) incl += tt;
  }
  int run = incl - s;
  for (int i = 0; i < K; ++i) if (base + i < nchunk) { bof[base + i] = run; run += btot[base + i]; }
}

// ---------------- K4: bucket edges by dst ----------------
__global__ __launch_bounds__(256) void fill_kernel(const int* __restrict__ src,
                                                   const int* __restrict__ dst,
                                                   const int* __restrict__ offsets,
                                                   const int* __restrict__ bof,
                                                   int* __restrict__ cursor,
                                                   int* __restrict__ srcl, int E)
{
  int e = blockIdx.x * 256 + threadIdx.x;
  if (e < E) {
    int d = dst[e];
    int p = offsets[d] + bof[d >> 10] + atomicAdd(&cursor[d], 1);
    srcl[p] = src[e];
  }
}

// ---------------- K5: per-(node,head) softmax aggregate, no online max ----------------
__global__ __launch_bounds__(256) void agg_kernel(
    const _Float16* __restrict__ feat16, const float* __restrict__ el,
    const float* __restrict__ er, const int* __restrict__ offsets,
    const int* __restrict__ bof, const int* __restrict__ srcl,
    const float* __restrict__ bias, float* __restrict__ hout, int N)
{
  int gid = blockIdx.x * 256 + threadIdx.x;
  if (gid >= N * NHEAD) return;
  const int n = gid >> 3, hh = gid & 7;
  const int o0 = offsets[n] + bof[n >> 10];
  const int o1 = offsets[n + 1] + bof[(n + 1) >> 10];
  const float er_nh = er[n * NHEAD + hh];

  float s = 0.f;
  float a[16];
  #pragma unroll
  for (int d = 0; d < 16; ++d) a[d] = 0.f;

  for (int j = o0; j < o1; ++j) {
    int sidx = srcl[j];
    float e = el[sidx * NHEAD + hh] + er_nh;
    e = e > 0.f ? e : 0.2f * e;
    float p = __expf(e);
    s += p;
    const half8* fp = (const half8*)(feat16 + (size_t)sidx * DD + hh * 16);
    half8 f0 = fp[0], f1 = fp[1];
    #pragma unroll
    for (int d = 0; d < 8; ++d) {
      a[d]     = fmaf(p, (float)f0[d], a[d]);
      a[d + 8] = fmaf(p, (float)f1[d], a[d + 8]);
    }
  }
  float inv = (o1 > o0) ? 1.f / s : 0.f;
  float* op = hout + (size_t)n * DD + hh * 16;
  const float* bp = bias + hh * 16;
  #pragma unroll
  for (int q = 0; q < 4; ++q) {
    float4 o;
    o.x = fmaf(a[q * 4 + 0], inv, bp[q * 4 + 0]);
    o.y = fmaf(a[q * 4 + 1], inv, bp[q * 4 + 1]);
    o.z = fmaf(a[q * 4 + 2], inv, bp[q * 4 + 2]);
    o.w = fmaf(a[q * 4 + 3], inv, bp[q * 4 + 3]);
    *(float4*)(op + q * 4) = o;
  }
}

// ---------------- K6: BN1 column stats ----------------
__global__ __launch_bounds__(256) void bnstats_kernel(
    const float* __restrict__ h, float* __restrict__ sums,
    float* __restrict__ sumsq, int N)
{
  __shared__ float rs[256], rss[256];
  const int c = threadIdx.x & 127;
  const int half = threadIdx.x >> 7;
  const int rowsPer = (N + gridDim.x - 1) / gridDim.x;
  const int r0 = blockIdx.x * rowsPer;
  const int r1 = min(N, r0 + rowsPer);
  float s = 0.f, ss = 0.f;
  for (int r = r0 + half; r < r1; r += 2) {
    float v = h[(size_t)r * DD + c];
    s += v; ss += v * v;
  }
  rs[threadIdx.x] = s; rss[threadIdx.x] = ss;
  __syncthreads();
  if (threadIdx.x < 128) {
    s = rs[threadIdx.x] + rs[threadIdx.x + 128];
    ss = rss[threadIdx.x] + rss[threadIdx.x + 128];
    atomicAdd(&sums[c], s);
    atomicAdd(&sumsq[c], ss);
  }
}

// ---------------- K7: wave-specialized MFMA MLP (barrier-free compute body) ----------------
// 32 rows/block, 4 waves; wave wv owns hidden chunk [wv*128, wv*128+128).
// GEMM1 -> private LDS slice (in-wave lgkmcnt only) -> GEMM2 partial -> LDS reduce.
__global__ __launch_bounds__(256, 2) void mlp_mfma_kernel(
    const float* __restrict__ hbuf, const float* __restrict__ sum1,
    const float* __restrict__ ss1, const float* __restrict__ bn1_g,
    const float* __restrict__ bn1_b, const _Float16* __restrict__ W1P,
    const _Float16* __restrict__ W2P, const float* __restrict__ b1,
    const float* __restrict__ b2, float* __restrict__ out,
    float* __restrict__ sums2, float* __restrict__ sumsq2, int N)
{
  __shared__ char smem[40960];           // As 8KB | Htr 4x8KB ; aliased by Red (16KB) later
  __shared__ float sc1[128], sh1[128];
  __shared__ float sumb[128], ssqb[128];
  char* As = smem;
  float* Red = (float*)smem;
  const int tid = threadIdx.x;
  const int wv = tid >> 6, lane = tid & 63;
  const int l15 = lane & 15, l4 = lane >> 4;
  const int n0 = blockIdx.x * 32;
  char* Htr = smem + 8192 + wv * 8192;

  if (tid < 128) {   // fold BN1-finalize: scale/shift from global stats
    float mean = sum1[tid] / (float)N;
    float var = ss1[tid] / (float)N - mean * mean;
    float sc = bn1_g[tid] * rsqrtf(var + 1e-5f);
    sc1[tid] = sc;
    sh1[tid] = bn1_b[tid] - mean * sc;
    sumb[tid] = 0.f; ssqb[tid] = 0.f;
  }
  __syncthreads();

  {  // stage A = f16(BN1(hbuf)): 8 threads/row, 16 f32 each -> 2 half8 swizzled stores
    const int row = tid >> 3;
    const int seg = tid & 7;
    const bool ok = (n0 + row) < N;
    const float* hp = hbuf + (size_t)(n0 + row) * DD + seg * 16;
    half8 h0, h1;
    #pragma unroll
    for (int c = 0; c < 16; ++c) {
      int col = seg * 16 + c;
      float v = ok ? hp[c] : 0.f;
      v = fmaf(v, sc1[col], sh1[col]);
      if (c < 8) h0[c] = (_Float16)v; else h1[c - 8] = (_Float16)v;
    }
    *(half8*)(As + swz256(row, seg * 32)) = h0;
    *(half8*)(As + swz256(row, seg * 32 + 16)) = h1;
  }
  __syncthreads();

  // A-fragments (held in regs, reused across all 8 nf)
  half8 af[2][4];
  #pragma unroll
  for (int mf = 0; mf < 2; ++mf)
    #pragma unroll
    for (int kc = 0; kc < 4; ++kc)
      af[mf][kc] = *(const half8*)(As + swz256(mf * 16 + l15, kc * 64 + l4 * 16));

  // GEMM1: this wave's 32x128 hidden chunk (no barriers)
  floatx4 acc1[2][8];
  #pragma unroll
  for (int mf = 0; mf < 2; ++mf)
    #pragma unroll
    for (int nf = 0; nf < 8; ++nf) acc1[mf][nf] = (floatx4)0.f;

  #pragma unroll
  for (int nf = 0; nf < 8; ++nf) {
    const int col = wv * 128 + nf * 16 + l15;
    #pragma unroll
    for (int kc = 0; kc < 4; ++kc) {
      half8 bf = *(const half8*)(W1P + (((size_t)kc * 512 + col) * 4 + l4) * 8);
      acc1[0][nf] = __builtin_amdgcn_mfma_f32_16x16x32_f16(af[0][kc], bf, acc1[0][nf], 0, 0, 0);
      acc1[1][nf] = __builtin_amdgcn_mfma_f32_16x16x32_f16(af[1][kc], bf, acc1[1][nf], 0, 0, 0);
    }
  }

  // relu + bias -> private LDS slice (f16, swizzled)
  #pragma unroll
  for (int nf = 0; nf < 8; ++nf) {
    const float bb = b1[wv * 128 + nf * 16 + l15];
    #pragma unroll
    for (int mf = 0; mf < 2; ++mf) {
      #pragma unroll
      for (int r = 0; r < 4; ++r) {
        float v = acc1[mf][nf][r] + bb;
        v = v > 0.f ? v : 0.f;
        *(_Float16*)(Htr + swz256(mf * 16 + l4 * 4 + r, (nf * 16 + l15) * 2)) = (_Float16)v;
      }
    }
  }

  // transpose-read own slice (in-wave lgkmcnt dependency only)
  half8 af2[2][4];
  #pragma unroll
  for (int mf = 0; mf < 2; ++mf)
    #pragma unroll
    for (int kc = 0; kc < 4; ++kc)
      af2[mf][kc] = *(const half8*)(Htr + swz256(mf * 16 + l15, kc * 64 + l4 * 16));

  // GEMM2 partial: K-chunk wv, full 32x128 output
  floatx4 acc2[2][8];
  #pragma unroll
  for (int mf = 0; mf < 2; ++mf)
    #pragma unroll
    for (int nf = 0; nf < 8; ++nf) acc2[mf][nf] = (floatx4)0.f;

  #pragma unroll
  for (int nf = 0; nf < 8; ++nf) {
    const int col = nf * 16 + l15;
    #pragma unroll
    for (int kc = 0; kc < 4; ++kc) {
      half8 bf = *(const half8*)(W2P + (((size_t)(wv * 4 + kc) * 128 + col) * 4 + l4) * 8);
      acc2[0][nf] = __builtin_amdgcn_mfma_f32_16x16x32_f16(af2[0][kc], bf, acc2[0][nf], 0, 0, 0);
      acc2[1][nf] = __builtin_amdgcn_mfma_f32_16x16x32_f16(af2[1][kc], bf, acc2[1][nf], 0, 0, 0);
    }
  }

  // cross-wave reduction in LDS (Red aliases As/Htr, dead now)
  __syncthreads();
  if (wv == 0) {
    #pragma unroll
    for (int mf = 0; mf < 2; ++mf)
      #pragma unroll
      for (int nf = 0; nf < 8; ++nf)
        #pragma unroll
        for (int r = 0; r < 4; ++r)
          Red[(mf * 16 + l4 * 4 + r) * 128 + nf * 16 + l15] = acc2[mf][nf][r];
  }
  __syncthreads();
  if (wv != 0) {
    #pragma unroll
    for (int mf = 0; mf < 2; ++mf)
      #pragma unroll
      for (int nf = 0; nf < 8; ++nf)
        #pragma unroll
        for (int r = 0; r < 4; ++r)
          atomicAdd(&Red[(mf * 16 + l4 * 4 + r) * 128 + nf * 16 + l15], acc2[mf][nf][r]);
  }
  __syncthreads();

  // epilogue: coalesced +b2 / store / BN2 column partial stats
  {
    const int row = tid >> 3, seg = tid & 7;
    const int n = n0 + row;
    float vals[16];
    #pragma unroll
    for (int q = 0; q < 4; ++q) {
      float4 v = *(const float4*)&Red[row * 128 + seg * 16 + q * 4];
      float4 bb = *(const float4*)&b2[seg * 16 + q * 4];
      v.x += bb.x; v.y += bb.y; v.z += bb.z; v.w += bb.w;
      if (n < N) *(float4*)&out[(size_t)n * DD + seg * 16 + q * 4] = v;
      else { v = make_float4(0.f, 0.f, 0.f, 0.f); }
      vals[q * 4 + 0] = v.x; vals[q * 4 + 1] = v.y; vals[q * 4 + 2] = v.z; vals[q * 4 + 3] = v.w;
    }
    // reduce over the 8 rows in this wave (lanes stride 8 share seg)
    #pragma unroll
    for (int c = 0; c < 16; ++c) {
      float s = vals[c], ssq = vals[c] * vals[c];
      s += __shfl_xor(s, 8, 64);  ssq += __shfl_xor(ssq, 8, 64);
      s += __shfl_xor(s, 16, 64); ssq += __shfl_xor(ssq, 16, 64);
      s += __shfl_xor(s, 32, 64); ssq += __shfl_xor(ssq, 32, 64);
      if (lane < 8) {
        atomicAdd(&sumb[lane * 16 + c], s);     // lane==seg here
        atomicAdd(&ssqb[lane * 16 + c], ssq);
      }
    }
  }
  __syncthreads();
  if (tid < 128) {
    atomicAdd(&sums2[tid], sumb[tid]);
    atomicAdd(&sumsq2[tid], ssqb[tid]);
  }
}

// ---------------- K8: BN2 finalize + apply in one pass ----------------
__global__ __launch_bounds__(256) void applybn_kernel(
    float* __restrict__ out, const float* __restrict__ sum2,
    const float* __restrict__ ss2, const float* __restrict__ gamma,
    const float* __restrict__ beta, int N, int total4)
{
  __shared__ float sc[128], sh[128];
  if (threadIdx.x < 128) {
    int c = threadIdx.x;
    float mean = sum2[c] / (float)N;
    float var = ss2[c] / (float)N - mean * mean;
    float s = gamma[c] * rsqrtf(var + 1e-5f);
    sc[c] = s;
    sh[c] = beta[c] - mean * s;
  }
  __syncthreads();
  int i = blockIdx.x * 256 + threadIdx.x;
  const int stride = gridDim.x * 256;
  for (; i < total4; i += stride) {
    float4 v = ((float4*)out)[i];
    int c = (i & 31) * 4;
    float4 scv = *(const float4*)&sc[c];
    float4 shv = *(const float4*)&sh[c];
    v.x = fmaf(v.x, scv.x, shv.x); v.y = fmaf(v.y, scv.y, shv.y);
    v.z = fmaf(v.z, scv.z, shv.z); v.w = fmaf(v.w, scv.w, shv.w);
    ((float4*)out)[i] = v;
  }
}

extern "C" void kernel_launch(void* const* d_in, const int* in_sizes, int n_in,
                              void* d_out, int out_size, void* d_ws, size_t ws_size,
                              hipStream_t stream) {
  const float* x        = (const float*)d_in[0];
  const int*   src      = (const int*)d_in[1];
  const int*   dst      = (const int*)d_in[2];
  const float* W        = (const float*)d_in[3];
  const float* attn_l   = (const float*)d_in[4];
  const float* attn_r   = (const float*)d_in[5];
  const float* bias_gat = (const float*)d_in[6];
  const float* bn1_g    = (const float*)d_in[7];
  const float* bn1_b    = (const float*)d_in[8];
  const float* W1       = (const float*)d_in[9];
  const float* b1       = (const float*)d_in[10];
  const float* W2       = (const float*)d_in[11];
  const float* b2       = (const float*)d_in[12];
  const float* bn2_g    = (const float*)d_in[13];
  const float* bn2_b    = (const float*)d_in[14];
  float* out = (float*)d_out;

  const int N = in_sizes[0] / DD;
  const int E = in_sizes[1];
  const int NPAD = ((N + 1023) / 1024) * 1024;
  const int NCHUNK = NPAD / 1024;

  // workspace layout
  _Float16* feat16 = (_Float16*)d_ws;                 // N*128 f16 (padded to even)
  float* hbuf = (float*)(feat16 + (size_t)((N + 1) & ~1) * DD);  // N*128 f32
  float* el   = hbuf + (size_t)N * DD;                // N*8
  float* er   = el + (size_t)N * NHEAD;               // N*8
  int* counts = (int*)(er + (size_t)N * NHEAD);       // NPAD
  int* cursor = counts + NPAD;                        // NPAD
  int* offsets = cursor + NPAD;                       // NPAD
  int* srcl   = offsets + NPAD;                       // E
  int* btot   = srcl + E;                             // 64
  int* bof    = btot + 64;                            // 64
  float* stats = (float*)(bof + 64);                  // 1024 floats
  float* sum1 = stats, *ss1 = stats + 128;
  float* sum2 = stats + 256, *ss2 = stats + 384;
  _Float16* WP  = (_Float16*)(stats + 1024);          // 16384 f16
  _Float16* W1P = WP + 4 * 128 * 32;                  // 65536 f16
  _Float16* W2P = W1P + 4 * 512 * 32;                 // 65536 f16

  hipMemsetAsync(counts, 0, (size_t)2 * NPAD * sizeof(int), stream);
  hipMemsetAsync(stats, 0, 512 * sizeof(float), stream);

  const int nblk32 = (N + 31) / 32;
  pack_kernel<<<256, 256, 0, stream>>>(W, W1, W2, WP, W1P, W2P);
  feat_mfma_kernel<<<nblk32, 256, 0, stream>>>(x, WP, attn_l, attn_r, feat16, el, er, N);
  count_kernel<<<(E + 255) / 256, 256, 0, stream>>>(dst, counts, E);
  scan1_kernel<<<NCHUNK, 256, 0, stream>>>(counts, offsets, btot);
  scan2_kernel<<<1, 64, 0, stream>>>(btot, bof, NCHUNK);
  fill_kernel<<<(E + 255) / 256, 256, 0, stream>>>(src, dst, offsets, bof, cursor, srcl, E);
  agg_kernel<<<(N * NHEAD + 255) / 256, 256, 0, stream>>>(feat16, el, er, offsets, bof,
                                                          srcl, bias_gat, hbuf, N);
  bnstats_kernel<<<256, 256, 0, stream>>>(hbuf, sum1, ss1, N);
  mlp_mfma_kernel<<<nblk32, 256, 0, stream>>>(hbuf, sum1, ss1, bn1_g, bn1_b, W1P, W2P,
                                              b1, b2, out, sum2, ss2, N);
  applybn_kernel<<<2048, 256, 0, stream>>>(out, sum2, ss2, bn2_g, bn2_b, N, N * DD / 4);
}

// Round 6
// 281.649 us; speedup vs baseline: 1.3647x; 1.3647x over previous
//
#include <hip/hip_runtime.h>
#include <math.h>

#define NHEAD 8
#define DD 128
#define HIDD 512

typedef _Float16 half8 __attribute__((ext_vector_type(8)));
typedef float floatx4 __attribute__((ext_vector_type(4)));

// XOR-swizzle (T2): spreads 16B chunks of different rows across bank quads.
__device__ __forceinline__ int swz256(int row, int bytecol) {  // 256B rows (128 f16)
  return row * 256 + (bytecol ^ ((row & 7) << 4));
}
__device__ __forceinline__ int swz512(int row, int bytecol) {  // 512B rows (128 f32)
  return row * 512 + (bytecol ^ ((row & 7) << 4));
}

// ---------------- K0: pack weights to f16, fragment-contiguous ----------------
__global__ __launch_bounds__(256) void pack_kernel(
    const float* __restrict__ W, const float* __restrict__ W1,
    const float* __restrict__ W2, _Float16* __restrict__ WP,
    _Float16* __restrict__ W1P, _Float16* __restrict__ W2P)
{
  int i = blockIdx.x * 256 + threadIdx.x;
  if (i < 4 * 128 * 4 * 8) {   // WP <- W[128][128]
    int ii = i & 7, l4 = (i >> 3) & 3, col = (i >> 5) & 127, kc = i >> 12;
    WP[i] = (_Float16)W[(kc * 32 + l4 * 8 + ii) * DD + col];
  }
  if (i < 4 * 512 * 4 * 8) {   // W1P <- W1[128][512]
    int ii = i & 7, l4 = (i >> 3) & 3, col = (i >> 5) & 511, kc = i >> 14;
    W1P[i] = (_Float16)W1[(kc * 32 + l4 * 8 + ii) * HIDD + col];
  }
  if (i < 16 * 128 * 4 * 8) {  // W2P <- W2[512][128]
    int ii = i & 7, l4 = (i >> 3) & 3, col = (i >> 5) & 127, kch = i >> 12;
    W2P[i] = (_Float16)W2[(kch * 32 + l4 * 8 + ii) * DD + col];
  }
}

// ---------------- K1: MFMA feat = f16(x @ W), el/er per (node, head). 32 rows/block ----------------
__global__ __launch_bounds__(256) void feat_mfma_kernel(
    const float* __restrict__ x, const _Float16* __restrict__ WP,
    const float* __restrict__ attn_l, const float* __restrict__ attn_r,
    _Float16* __restrict__ feat16, float* __restrict__ el, float* __restrict__ er, int N)
{
  __shared__ char xs[32 * 512];   // 16KB swizzled f32 A-tile
  const int tid = threadIdx.x;
  const int wv = tid >> 6, lane = tid & 63;
  const int l15 = lane & 15, l4 = lane >> 4;
  const int n0 = blockIdx.x * 32;

  {  // stage x: 8 threads/row, 4 x 16B each, coalesced global, swizzled LDS
    const int row = tid >> 3;
    const int seg = tid & 7;
    const bool ok = (n0 + row) < N;
    const float4* srcp = (const float4*)(x + (size_t)(n0 + row) * DD + seg * 16);
    const float4 z = make_float4(0.f, 0.f, 0.f, 0.f);
    #pragma unroll
    for (int c = 0; c < 4; ++c) {
      float4 v = ok ? srcp[c] : z;
      *(float4*)(xs + swz512(row, seg * 64 + c * 16)) = v;
    }
  }
  __syncthreads();

  floatx4 acc[2][2];
  #pragma unroll
  for (int mf = 0; mf < 2; ++mf) { acc[mf][0] = (floatx4)0.f; acc[mf][1] = (floatx4)0.f; }

  #pragma unroll
  for (int kc = 0; kc < 4; ++kc) {
    half8 b0 = *(const half8*)(WP + ((kc * 128 + wv * 32 + l15) * 4 + l4) * 8);
    half8 b1 = *(const half8*)(WP + ((kc * 128 + wv * 32 + 16 + l15) * 4 + l4) * 8);
    #pragma unroll
    for (int mf = 0; mf < 2; ++mf) {
      const int row = mf * 16 + l15;
      float4 a0 = *(const float4*)(xs + swz512(row, kc * 128 + l4 * 32));
      float4 a1 = *(const float4*)(xs + swz512(row, kc * 128 + l4 * 32 + 16));
      half8 af;
      af[0] = (_Float16)a0.x; af[1] = (_Float16)a0.y; af[2] = (_Float16)a0.z; af[3] = (_Float16)a0.w;
      af[4] = (_Float16)a1.x; af[5] = (_Float16)a1.y; af[6] = (_Float16)a1.z; af[7] = (_Float16)a1.w;
      acc[mf][0] = __builtin_amdgcn_mfma_f32_16x16x32_f16(af, b0, acc[mf][0], 0, 0, 0);
      acc[mf][1] = __builtin_amdgcn_mfma_f32_16x16x32_f16(af, b1, acc[mf][1], 0, 0, 0);
    }
  }

  // epilogue: store feat16; el/er = 16-lane shfl reduction per row/head
  const float al0 = attn_l[wv * 32 + l15], al1 = attn_l[wv * 32 + 16 + l15];
  const float ar0 = attn_r[wv * 32 + l15], ar1 = attn_r[wv * 32 + 16 + l15];
  #pragma unroll
  for (int mf = 0; mf < 2; ++mf) {
    #pragma unroll
    for (int r = 0; r < 4; ++r) {
      const int row = n0 + mf * 16 + l4 * 4 + r;
      float v0 = acc[mf][0][r], v1 = acc[mf][1][r];
      float e0l = v0 * al0, e0r = v0 * ar0;
      float e1l = v1 * al1, e1r = v1 * ar1;
      #pragma unroll
      for (int d = 1; d < 16; d <<= 1) {
        e0l += __shfl_xor(e0l, d, 64); e0r += __shfl_xor(e0r, d, 64);
        e1l += __shfl_xor(e1l, d, 64); e1r += __shfl_xor(e1r, d, 64);
      }
      if (row < N) {
        feat16[(size_t)row * DD + wv * 32 + l15] = (_Float16)v0;
        feat16[(size_t)row * DD + wv * 32 + 16 + l15] = (_Float16)v1;
        if (l15 == 0) {
          el[row * NHEAD + wv * 2] = e0l;     er[row * NHEAD + wv * 2] = e0r;
          el[row * NHEAD + wv * 2 + 1] = e1l; er[row * NHEAD + wv * 2 + 1] = e1r;
        }
      }
    }
  }
}

// ---------------- K2: in-degree histogram ----------------
__global__ __launch_bounds__(256) void count_kernel(const int* __restrict__ dst,
                                                    int* __restrict__ counts, int E)
{
  int e = blockIdx.x * 256 + threadIdx.x;
  if (e < E) atomicAdd(&counts[dst[e]], 1);
}

// ---------------- K3a: per-1024-chunk local exclusive scan + chunk totals ----------------
__global__ __launch_bounds__(256) void scan1_kernel(const int* __restrict__ counts,
                                                    int* __restrict__ offsets,
                                                    int* __restrict__ btot)
{
  __shared__ int wsum[4];
  const int lane = threadIdx.x & 63;
  const int wid = threadIdx.x >> 6;
  int4 c = *(const int4*)(counts + blockIdx.x * 1024 + threadIdx.x * 4);
  int q = c.x + c.y + c.z + c.w;
  int incl = q;
  #pragma unroll
  for (int d = 1; d < 64; d <<= 1) {
    int t = __shfl_up(incl, d, 64);
    if (lane >= d) incl += t;
  }
  if (lane == 63) wsum[wid] = incl;
  __syncthreads();
  int wprefix = 0;
  for (int w = 0; w < wid; ++w) wprefix += wsum[w];
  int excl = wprefix + incl - q;
  int4 o;
  o.x = excl; o.y = excl + c.x; o.z = o.y + c.y; o.w = o.z + c.z;
  *(int4*)(offsets + blockIdx.x * 1024 + threadIdx.x * 4) = o;
  if (threadIdx.x == 0) btot[blockIdx.x] = wsum[0] + wsum[1] + wsum[2] + wsum[3];
}

// ---------------- K3b: exclusive scan of chunk totals (1 wave) ----------------
__global__ __launch_bounds__(64) void scan2_kernel(const int* __restrict__ btot,
                                                   int* __restrict__ bof, int nchunk)
{
  const int t = threadIdx.x;
  const int K = (nchunk + 63) >> 6;
  const int base = t * K;
  int s = 0;
  for (int i = 0; i < K; ++i) if (base + i < nchunk) s += btot[base + i];
  int incl = s;
  #pragma unroll
  for (int d = 1; d < 64; d <<= 1) {
    int tt = __shfl_up(incl, d, 64);
    if (t >= d) incl += tt;
  }
  int run = incl - s;
  for (int i = 0; i < K; ++i) if (base + i < nchunk) { bof[base + i] = run; run += btot[base + i]; }
}

// ---------------- K4: bucket edges by dst ----------------
__global__ __launch_bounds__(256) void fill_kernel(const int* __restrict__ src,
                                                   const int* __restrict__ dst,
                                                   const int* __restrict__ offsets,
                                                   const int* __restrict__ bof,
                                                   int* __restrict__ cursor,
                                                   int* __restrict__ srcl, int E)
{
  int e = blockIdx.x * 256 + threadIdx.x;
  if (e < E) {
    int d = dst[e];
    int p = offsets[d] + bof[d >> 10] + atomicAdd(&cursor[d], 1);
    srcl[p] = src[e];
  }
}

// ---------------- K5: per-(node,head) softmax aggregate, no online max ----------------
__global__ __launch_bounds__(256) void agg_kernel(
    const _Float16* __restrict__ feat16, const float* __restrict__ el,
    const float* __restrict__ er, const int* __restrict__ offsets,
    const int* __restrict__ bof, const int* __restrict__ srcl,
    const float* __restrict__ bias, float* __restrict__ hout, int N)
{
  int gid = blockIdx.x * 256 + threadIdx.x;
  if (gid >= N * NHEAD) return;
  const int n = gid >> 3, hh = gid & 7;
  const int o0 = offsets[n] + bof[n >> 10];
  const int o1 = offsets[n + 1] + bof[(n + 1) >> 10];
  const float er_nh = er[n * NHEAD + hh];

  float s = 0.f;
  float a[16];
  #pragma unroll
  for (int d = 0; d < 16; ++d) a[d] = 0.f;

  for (int j = o0; j < o1; ++j) {
    int sidx = srcl[j];
    float e = el[sidx * NHEAD + hh] + er_nh;
    e = e > 0.f ? e : 0.2f * e;
    float p = __expf(e);
    s += p;
    const half8* fp = (const half8*)(feat16 + (size_t)sidx * DD + hh * 16);
    half8 f0 = fp[0], f1 = fp[1];
    #pragma unroll
    for (int d = 0; d < 8; ++d) {
      a[d]     = fmaf(p, (float)f0[d], a[d]);
      a[d + 8] = fmaf(p, (float)f1[d], a[d + 8]);
    }
  }
  float inv = (o1 > o0) ? 1.f / s : 0.f;
  float* op = hout + (size_t)n * DD + hh * 16;
  const float* bp = bias + hh * 16;
  #pragma unroll
  for (int q = 0; q < 4; ++q) {
    float4 o;
    o.x = fmaf(a[q * 4 + 0], inv, bp[q * 4 + 0]);
    o.y = fmaf(a[q * 4 + 1], inv, bp[q * 4 + 1]);
    o.z = fmaf(a[q * 4 + 2], inv, bp[q * 4 + 2]);
    o.w = fmaf(a[q * 4 + 3], inv, bp[q * 4 + 3]);
    *(float4*)(op + q * 4) = o;
  }
}

// ---------------- K6: BN column stats (used for BN1 on hbuf and BN2 on out) ----------------
__global__ __launch_bounds__(256) void bnstats_kernel(
    const float* __restrict__ h, float* __restrict__ sums,
    float* __restrict__ sumsq, int N)
{
  __shared__ float rs[256], rss[256];
  const int c = threadIdx.x & 127;
  const int half = threadIdx.x >> 7;
  const int rowsPer = (N + gridDim.x - 1) / gridDim.x;
  const int r0 = blockIdx.x * rowsPer;
  const int r1 = min(N, r0 + rowsPer);
  float s = 0.f, ss = 0.f;
  for (int r = r0 + half; r < r1; r += 2) {
    float v = h[(size_t)r * DD + c];
    s += v; ss += v * v;
  }
  rs[threadIdx.x] = s; rss[threadIdx.x] = ss;
  __syncthreads();
  if (threadIdx.x < 128) {
    s = rs[threadIdx.x] + rs[threadIdx.x + 128];
    ss = rss[threadIdx.x] + rss[threadIdx.x + 128];
    atomicAdd(&sums[c], s);
    atomicAdd(&sumsq[c], ss);
  }
}

// ---------------- K7: wave-specialized MFMA MLP, atomic-free ----------------
// 32 rows/block, 4 waves; wave wv owns hidden chunk [wv*128, wv*128+128).
// GEMM1 -> private LDS slice -> GEMM2 K-chunk partial -> plain-store LDS exchange -> sum.
// 4 barriers/block total, zero atomics. out = pre-BN2 (stats via separate bnstats pass).
__global__ __launch_bounds__(256) void mlp_mfma_kernel(
    const float* __restrict__ hbuf, const float* __restrict__ sum1,
    const float* __restrict__ ss1, const float* __restrict__ bn1_g,
    const float* __restrict__ bn1_b, const _Float16* __restrict__ W1P,
    const _Float16* __restrict__ W2P, const float* __restrict__ b1,
    const float* __restrict__ b2, float* __restrict__ out, int N)
{
  __shared__ char smem[40960];   // As 8KB | Htr 4x8KB ; Xch (32KB) aliases As+Htr[0..2]
  __shared__ float sc1[128], sh1[128];
  char* As = smem;
  char* Htr = smem + 8192;       // + wv*8192
  char* Xch = smem;              // [src wave][32 rows][128 cols] f16, swizzled
  const int tid = threadIdx.x;
  const int wv = tid >> 6, lane = tid & 63;
  const int l15 = lane & 15, l4 = lane >> 4;
  const int n0 = blockIdx.x * 32;

  if (tid < 128) {   // fold BN1-finalize
    float mean = sum1[tid] / (float)N;
    float var = ss1[tid] / (float)N - mean * mean;
    float sc = bn1_g[tid] * rsqrtf(var + 1e-5f);
    sc1[tid] = sc;
    sh1[tid] = bn1_b[tid] - mean * sc;
  }
  __syncthreads();   // B1

  {  // stage A = f16(BN1(hbuf)), swizzled
    const int row = tid >> 3;
    const int seg = tid & 7;
    const bool ok = (n0 + row) < N;
    const float* hp = hbuf + (size_t)(n0 + row) * DD + seg * 16;
    half8 h0, h1;
    #pragma unroll
    for (int c = 0; c < 16; ++c) {
      int col = seg * 16 + c;
      float v = ok ? hp[c] : 0.f;
      v = fmaf(v, sc1[col], sh1[col]);
      if (c < 8) h0[c] = (_Float16)v; else h1[c - 8] = (_Float16)v;
    }
    *(half8*)(As + swz256(row, seg * 32)) = h0;
    *(half8*)(As + swz256(row, seg * 32 + 16)) = h1;
  }
  __syncthreads();   // B2

  // A-fragments in regs
  half8 af[2][4];
  #pragma unroll
  for (int mf = 0; mf < 2; ++mf)
    #pragma unroll
    for (int kc = 0; kc < 4; ++kc)
      af[mf][kc] = *(const half8*)(As + swz256(mf * 16 + l15, kc * 64 + l4 * 16));

  // GEMM1 per-nf (acc not held): hidden chunk -> private LDS slice (in-wave only)
  char* myH = Htr + wv * 8192;
  #pragma unroll
  for (int nf = 0; nf < 8; ++nf) {
    floatx4 a0 = (floatx4)0.f, a1 = (floatx4)0.f;
    #pragma unroll
    for (int kc = 0; kc < 4; ++kc) {
      half8 bf = *(const half8*)(W1P + (((size_t)kc * 512 + wv * 128 + nf * 16 + l15) * 4 + l4) * 8);
      a0 = __builtin_amdgcn_mfma_f32_16x16x32_f16(af[0][kc], bf, a0, 0, 0, 0);
      a1 = __builtin_amdgcn_mfma_f32_16x16x32_f16(af[1][kc], bf, a1, 0, 0, 0);
    }
    const float bb = b1[wv * 128 + nf * 16 + l15];
    #pragma unroll
    for (int r = 0; r < 4; ++r) {
      float v0 = a0[r] + bb; v0 = v0 > 0.f ? v0 : 0.f;
      float v1 = a1[r] + bb; v1 = v1 > 0.f ? v1 : 0.f;
      *(_Float16*)(myH + swz256(l4 * 4 + r,      (nf * 16 + l15) * 2)) = (_Float16)v0;
      *(_Float16*)(myH + swz256(16 + l4 * 4 + r, (nf * 16 + l15) * 2)) = (_Float16)v1;
    }
  }

  // transpose-read own slice (in-wave lgkmcnt only)
  half8 af2[2][4];
  #pragma unroll
  for (int mf = 0; mf < 2; ++mf)
    #pragma unroll
    for (int kc = 0; kc < 4; ++kc)
      af2[mf][kc] = *(const half8*)(myH + swz256(mf * 16 + l15, kc * 64 + l4 * 16));

  // GEMM2 partial: K-chunk wv, full 32x128 output
  floatx4 acc2[2][8];
  #pragma unroll
  for (int mf = 0; mf < 2; ++mf)
    #pragma unroll
    for (int nf = 0; nf < 8; ++nf) acc2[mf][nf] = (floatx4)0.f;

  #pragma unroll
  for (int nf = 0; nf < 8; ++nf) {
    #pragma unroll
    for (int kc = 0; kc < 4; ++kc) {
      half8 bf = *(const half8*)(W2P + (((size_t)(wv * 4 + kc) * 128 + nf * 16 + l15) * 4 + l4) * 8);
      acc2[0][nf] = __builtin_amdgcn_mfma_f32_16x16x32_f16(af2[0][kc], bf, acc2[0][nf], 0, 0, 0);
      acc2[1][nf] = __builtin_amdgcn_mfma_f32_16x16x32_f16(af2[1][kc], bf, acc2[1][nf], 0, 0, 0);
    }
  }

  __syncthreads();   // B3: everyone done with As/Htr reads -> safe to overwrite as Xch

  // plain-store exchange: wave wv writes its f16 partial to Xch[wv]
  {
    char* myX = Xch + wv * 8192;
    #pragma unroll
    for (int nf = 0; nf < 8; ++nf) {
      const int col2 = (nf * 16 + l15) * 2;
      #pragma unroll
      for (int mf = 0; mf < 2; ++mf) {
        #pragma unroll
        for (int r = 0; r < 4; ++r)
          *(_Float16*)(myX + swz256(mf * 16 + l4 * 4 + r, col2)) = (_Float16)acc2[mf][nf][r];
      }
    }
  }
  __syncthreads();   // B4

  // reduce 4 partials + b2, coalesced store
  {
    const int row = tid >> 3, seg = tid & 7;
    const int n = n0 + row;
    if (n < N) {
      float accv[16];
      #pragma unroll
      for (int c = 0; c < 16; ++c) accv[c] = b2[seg * 16 + c];
      #pragma unroll
      for (int s = 0; s < 4; ++s) {
        half8 ha = *(const half8*)(Xch + s * 8192 + swz256(row, seg * 32));
        half8 hb = *(const half8*)(Xch + s * 8192 + swz256(row, seg * 32 + 16));
        #pragma unroll
        for (int j = 0; j < 8; ++j) {
          accv[j] += (float)ha[j];
          accv[8 + j] += (float)hb[j];
        }
      }
      #pragma unroll
      for (int q = 0; q < 4; ++q) {
        float4 v = make_float4(accv[q * 4], accv[q * 4 + 1], accv[q * 4 + 2], accv[q * 4 + 3]);
        *(float4*)&out[(size_t)n * DD + seg * 16 + q * 4] = v;
      }
    }
  }
}

// ---------------- K8: BN2 finalize + apply in one pass ----------------
__global__ __launch_bounds__(256) void applybn_kernel(
    float* __restrict__ out, const float* __restrict__ sum2,
    const float* __restrict__ ss2, const float* __restrict__ gamma,
    const float* __restrict__ beta, int N, int total4)
{
  __shared__ float sc[128], sh[128];
  if (threadIdx.x < 128) {
    int c = threadIdx.x;
    float mean = sum2[c] / (float)N;
    float var = ss2[c] / (float)N - mean * mean;
    float s = gamma[c] * rsqrtf(var + 1e-5f);
    sc[c] = s;
    sh[c] = beta[c] - mean * s;
  }
  __syncthreads();
  int i = blockIdx.x * 256 + threadIdx.x;
  const int stride = gridDim.x * 256;
  for (; i < total4; i += stride) {
    float4 v = ((float4*)out)[i];
    int c = (i & 31) * 4;
    float4 scv = *(const float4*)&sc[c];
    float4 shv = *(const float4*)&sh[c];
    v.x = fmaf(v.x, scv.x, shv.x); v.y = fmaf(v.y, scv.y, shv.y);
    v.z = fmaf(v.z, scv.z, shv.z); v.w = fmaf(v.w, scv.w, shv.w);
    ((float4*)out)[i] = v;
  }
}

extern "C" void kernel_launch(void* const* d_in, const int* in_sizes, int n_in,
                              void* d_out, int out_size, void* d_ws, size_t ws_size,
                              hipStream_t stream) {
  const float* x        = (const float*)d_in[0];
  const int*   src      = (const int*)d_in[1];
  const int*   dst      = (const int*)d_in[2];
  const float* W        = (const float*)d_in[3];
  const float* attn_l   = (const float*)d_in[4];
  const float* attn_r   = (const float*)d_in[5];
  const float* bias_gat = (const float*)d_in[6];
  const float* bn1_g    = (const float*)d_in[7];
  const float* bn1_b    = (const float*)d_in[8];
  const float* W1       = (const float*)d_in[9];
  const float* b1       = (const float*)d_in[10];
  const float* W2       = (const float*)d_in[11];
  const float* b2       = (const float*)d_in[12];
  const float* bn2_g    = (const float*)d_in[13];
  const float* bn2_b    = (const float*)d_in[14];
  float* out = (float*)d_out;

  const int N = in_sizes[0] / DD;
  const int E = in_sizes[1];
  const int NPAD = ((N + 1023) / 1024) * 1024;
  const int NCHUNK = NPAD / 1024;

  // workspace layout
  _Float16* feat16 = (_Float16*)d_ws;                 // N*128 f16 (padded to even)
  float* hbuf = (float*)(feat16 + (size_t)((N + 1) & ~1) * DD);  // N*128 f32
  float* el   = hbuf + (size_t)N * DD;                // N*8
  float* er   = el + (size_t)N * NHEAD;               // N*8
  int* counts = (int*)(er + (size_t)N * NHEAD);       // NPAD
  int* cursor = counts + NPAD;                        // NPAD
  int* offsets = cursor + NPAD;                       // NPAD
  int* srcl   = offsets + NPAD;                       // E
  int* btot   = srcl + E;                             // 64
  int* bof    = btot + 64;                            // 64
  float* stats = (float*)(bof + 64);                  // 1024 floats
  float* sum1 = stats, *ss1 = stats + 128;
  float* sum2 = stats + 256, *ss2 = stats + 384;
  _Float16* WP  = (_Float16*)(stats + 1024);          // 16384 f16
  _Float16* W1P = WP + 4 * 128 * 32;                  // 65536 f16
  _Float16* W2P = W1P + 4 * 512 * 32;                 // 65536 f16

  hipMemsetAsync(counts, 0, (size_t)2 * NPAD * sizeof(int), stream);
  hipMemsetAsync(stats, 0, 512 * sizeof(float), stream);

  const int nblk32 = (N + 31) / 32;
  pack_kernel<<<256, 256, 0, stream>>>(W, W1, W2, WP, W1P, W2P);
  feat_mfma_kernel<<<nblk32, 256, 0, stream>>>(x, WP, attn_l, attn_r, feat16, el, er, N);
  count_kernel<<<(E + 255) / 256, 256, 0, stream>>>(dst, counts, E);
  scan1_kernel<<<NCHUNK, 256, 0, stream>>>(counts, offsets, btot);
  scan2_kernel<<<1, 64, 0, stream>>>(btot, bof, NCHUNK);
  fill_kernel<<<(E + 255) / 256, 256, 0, stream>>>(src, dst, offsets, bof, cursor, srcl, E);
  agg_kernel<<<(N * NHEAD + 255) / 256, 256, 0, stream>>>(feat16, el, er, offsets, bof,
                                                          srcl, bias_gat, hbuf, N);
  bnstats_kernel<<<256, 256, 0, stream>>>(hbuf, sum1, ss1, N);
  mlp_mfma_kernel<<<nblk32, 256, 0, stream>>>(hbuf, sum1, ss1, bn1_g, bn1_b, W1P, W2P,
                                              b1, b2, out, N);
  bnstats_kernel<<<256, 256, 0, stream>>>(out, sum2, ss2, N);
  applybn_kernel<<<2048, 256, 0, stream>>>(out, sum2, ss2, bn2_g, bn2_b, N, N * DD / 4);
}

// Round 7
// 276.812 us; speedup vs baseline: 1.3886x; 1.0175x over previous
//
#include <hip/hip_runtime.h>
#include <math.h>

#define NHEAD 8
#define DD 128
#define HIDD 512
#define NB 768   // persistent grid: 3 blocks/CU

typedef _Float16 half8 __attribute__((ext_vector_type(8)));
typedef float floatx4 __attribute__((ext_vector_type(4)));

// XOR-swizzle: 16-row spread across 16B slots (4-way max alias on frag reads).
__device__ __forceinline__ int swz256(int row, int bytecol) {  // 256B rows (128 f16)
  return row * 256 + (bytecol ^ ((row & 15) << 4));
}
__device__ __forceinline__ int swz512(int row, int bytecol) {  // 512B rows (128 f32)
  return row * 512 + (bytecol ^ ((row & 15) << 4));
}

// ---------------- K0: pack weights to f16, fragment-contiguous ----------------
__global__ __launch_bounds__(256) void pack_kernel(
    const float* __restrict__ W, const float* __restrict__ W1,
    const float* __restrict__ W2, _Float16* __restrict__ WP,
    _Float16* __restrict__ W1P, _Float16* __restrict__ W2P)
{
  int i = blockIdx.x * 256 + threadIdx.x;
  if (i < 4 * 128 * 4 * 8) {   // WP <- W[128][128]
    int ii = i & 7, l4 = (i >> 3) & 3, col = (i >> 5) & 127, kc = i >> 12;
    WP[i] = (_Float16)W[(kc * 32 + l4 * 8 + ii) * DD + col];
  }
  if (i < 4 * 512 * 4 * 8) {   // W1P <- W1[128][512]
    int ii = i & 7, l4 = (i >> 3) & 3, col = (i >> 5) & 511, kc = i >> 14;
    W1P[i] = (_Float16)W1[(kc * 32 + l4 * 8 + ii) * HIDD + col];
  }
  if (i < 16 * 128 * 4 * 8) {  // W2P <- W2[512][128]
    int ii = i & 7, l4 = (i >> 3) & 3, col = (i >> 5) & 127, kch = i >> 12;
    W2P[i] = (_Float16)W2[(kch * 32 + l4 * 8 + ii) * DD + col];
  }
}

// ---------------- K1: persistent MFMA feat = f16(x @ W) + el/er ----------------
__global__ __launch_bounds__(256) void feat_mfma_kernel(
    const float* __restrict__ x, const _Float16* __restrict__ WP,
    const float* __restrict__ attn_l, const float* __restrict__ attn_r,
    _Float16* __restrict__ feat16, float* __restrict__ el, float* __restrict__ er,
    int N, int T)
{
  __shared__ char xs[32 * 512];   // 16KB swizzled f32 A-tile
  const int tid = threadIdx.x;
  const int wv = tid >> 6, lane = tid & 63;
  const int l15 = lane & 15, l4 = lane >> 4;
  const int row = tid >> 3, seg = tid & 7;

  const float al0 = attn_l[wv * 32 + l15], al1 = attn_l[wv * 32 + 16 + l15];
  const float ar0 = attn_r[wv * 32 + l15], ar1 = attn_r[wv * 32 + 16 + l15];

  int t = blockIdx.x;
  float4 pre[4];
  {
    const int n = t * 32 + row;
    const bool ok = (t < T) && (n < N);
    const float4* sp = (const float4*)(x + (size_t)n * DD + seg * 16);
    const float4 z = make_float4(0.f, 0.f, 0.f, 0.f);
    #pragma unroll
    for (int c = 0; c < 4; ++c) pre[c] = ok ? sp[c] : z;
  }

  for (; t < T; t += NB) {
    const int n0 = t * 32;
    #pragma unroll
    for (int c = 0; c < 4; ++c)
      *(float4*)(xs + swz512(row, seg * 64 + c * 16)) = pre[c];
    __syncthreads();

    floatx4 acc[2][2];
    #pragma unroll
    for (int mf = 0; mf < 2; ++mf) { acc[mf][0] = (floatx4)0.f; acc[mf][1] = (floatx4)0.f; }

    #pragma unroll
    for (int kc = 0; kc < 4; ++kc) {
      half8 b0 = *(const half8*)(WP + ((kc * 128 + wv * 32 + l15) * 4 + l4) * 8);
      half8 b1 = *(const half8*)(WP + ((kc * 128 + wv * 32 + 16 + l15) * 4 + l4) * 8);
      #pragma unroll
      for (int mf = 0; mf < 2; ++mf) {
        const int rr = mf * 16 + l15;
        float4 a0 = *(const float4*)(xs + swz512(rr, kc * 128 + l4 * 32));
        float4 a1 = *(const float4*)(xs + swz512(rr, kc * 128 + l4 * 32 + 16));
        half8 af;
        af[0] = (_Float16)a0.x; af[1] = (_Float16)a0.y; af[2] = (_Float16)a0.z; af[3] = (_Float16)a0.w;
        af[4] = (_Float16)a1.x; af[5] = (_Float16)a1.y; af[6] = (_Float16)a1.z; af[7] = (_Float16)a1.w;
        acc[mf][0] = __builtin_amdgcn_mfma_f32_16x16x32_f16(af, b0, acc[mf][0], 0, 0, 0);
        acc[mf][1] = __builtin_amdgcn_mfma_f32_16x16x32_f16(af, b1, acc[mf][1], 0, 0, 0);
      }
    }

    {  // prefetch next tile (issued after all W loads; overlaps epilogue + next stage)
      const int tn = t + NB;
      const int n = tn * 32 + row;
      const bool ok = (tn < T) && (n < N);
      const float4* sp = (const float4*)(x + (size_t)n * DD + seg * 16);
      const float4 z = make_float4(0.f, 0.f, 0.f, 0.f);
      #pragma unroll
      for (int c = 0; c < 4; ++c) pre[c] = ok ? sp[c] : z;
    }

    // epilogue: store feat16; el/er via 16-lane shfl reduction
    #pragma unroll
    for (int mf = 0; mf < 2; ++mf) {
      #pragma unroll
      for (int r = 0; r < 4; ++r) {
        const int rown = n0 + mf * 16 + l4 * 4 + r;
        float v0 = acc[mf][0][r], v1 = acc[mf][1][r];
        float e0l = v0 * al0, e0r = v0 * ar0;
        float e1l = v1 * al1, e1r = v1 * ar1;
        #pragma unroll
        for (int d = 1; d < 16; d <<= 1) {
          e0l += __shfl_xor(e0l, d, 64); e0r += __shfl_xor(e0r, d, 64);
          e1l += __shfl_xor(e1l, d, 64); e1r += __shfl_xor(e1r, d, 64);
        }
        if (rown < N) {
          feat16[(size_t)rown * DD + wv * 32 + l15] = (_Float16)v0;
          feat16[(size_t)rown * DD + wv * 32 + 16 + l15] = (_Float16)v1;
          if (l15 == 0) {
            el[rown * NHEAD + wv * 2] = e0l;     er[rown * NHEAD + wv * 2] = e0r;
            el[rown * NHEAD + wv * 2 + 1] = e1l; er[rown * NHEAD + wv * 2 + 1] = e1r;
          }
        }
      }
    }
    __syncthreads();   // xs reads done before next stage overwrites
  }
}

// ---------------- K2: in-degree histogram ----------------
__global__ __launch_bounds__(256) void count_kernel(const int* __restrict__ dst,
                                                    int* __restrict__ counts, int E)
{
  int e = blockIdx.x * 256 + threadIdx.x;
  if (e < E) atomicAdd(&counts[dst[e]], 1);
}

// ---------------- K3a: per-1024-chunk local exclusive scan + chunk totals ----------------
__global__ __launch_bounds__(256) void scan1_kernel(const int* __restrict__ counts,
                                                    int* __restrict__ offsets,
                                                    int* __restrict__ btot)
{
  __shared__ int wsum[4];
  const int lane = threadIdx.x & 63;
  const int wid = threadIdx.x >> 6;
  int4 c = *(const int4*)(counts + blockIdx.x * 1024 + threadIdx.x * 4);
  int q = c.x + c.y + c.z + c.w;
  int incl = q;
  #pragma unroll
  for (int d = 1; d < 64; d <<= 1) {
    int t = __shfl_up(incl, d, 64);
    if (lane >= d) incl += t;
  }
  if (lane == 63) wsum[wid] = incl;
  __syncthreads();
  int wprefix = 0;
  for (int w = 0; w < wid; ++w) wprefix += wsum[w];
  int excl = wprefix + incl - q;
  int4 o;
  o.x = excl; o.y = excl + c.x; o.z = o.y + c.y; o.w = o.z + c.z;
  *(int4*)(offsets + blockIdx.x * 1024 + threadIdx.x * 4) = o;
  if (threadIdx.x == 0) btot[blockIdx.x] = wsum[0] + wsum[1] + wsum[2] + wsum[3];
}

// ---------------- K3b: exclusive scan of chunk totals (1 wave) ----------------
__global__ __launch_bounds__(64) void scan2_kernel(const int* __restrict__ btot,
                                                   int* __restrict__ bof, int nchunk)
{
  const int t = threadIdx.x;
  const int K = (nchunk + 63) >> 6;
  const int base = t * K;
  int s = 0;
  for (int i = 0; i < K; ++i) if (base + i < nchunk) s += btot[base + i];
  int incl = s;
  #pragma unroll
  for (int d = 1; d < 64; d <<= 1) {
    int tt = __shfl_up(incl, d, 64);
    if (t >= d) incl += tt;
  }
  int run = incl - s;
  for (int i = 0; i < K; ++i) if (base + i < nchunk) { bof[base + i] = run; run += btot[base + i]; }
}

// ---------------- K4: bucket edges by dst ----------------
__global__ __launch_bounds__(256) void fill_kernel(const int* __restrict__ src,
                                                   const int* __restrict__ dst,
                                                   const int* __restrict__ offsets,
                                                   const int* __restrict__ bof,
                                                   int* __restrict__ cursor,
                                                   int* __restrict__ srcl, int E)
{
  int e = blockIdx.x * 256 + threadIdx.x;
  if (e < E) {
    int d = dst[e];
    int p = offsets[d] + bof[d >> 10] + atomicAdd(&cursor[d], 1);
    srcl[p] = src[e];
  }
}

// ---------------- K5: per-(node,head) softmax aggregate, no online max ----------------
__global__ __launch_bounds__(256) void agg_kernel(
    const _Float16* __restrict__ feat16, const float* __restrict__ el,
    const float* __restrict__ er, const int* __restrict__ offsets,
    const int* __restrict__ bof, const int* __restrict__ srcl,
    const float* __restrict__ bias, float* __restrict__ hout, int N)
{
  int gid = blockIdx.x * 256 + threadIdx.x;
  if (gid >= N * NHEAD) return;
  const int n = gid >> 3, hh = gid & 7;
  const int o0 = offsets[n] + bof[n >> 10];
  const int o1 = offsets[n + 1] + bof[(n + 1) >> 10];
  const float er_nh = er[n * NHEAD + hh];

  float s = 0.f;
  float a[16];
  #pragma unroll
  for (int d = 0; d < 16; ++d) a[d] = 0.f;

  for (int j = o0; j < o1; ++j) {
    int sidx = srcl[j];
    float e = el[sidx * NHEAD + hh] + er_nh;
    e = e > 0.f ? e : 0.2f * e;
    float p = __expf(e);
    s += p;
    const half8* fp = (const half8*)(feat16 + (size_t)sidx * DD + hh * 16);
    half8 f0 = fp[0], f1 = fp[1];
    #pragma unroll
    for (int d = 0; d < 8; ++d) {
      a[d]     = fmaf(p, (float)f0[d], a[d]);
      a[d + 8] = fmaf(p, (float)f1[d], a[d + 8]);
    }
  }
  float inv = (o1 > o0) ? 1.f / s : 0.f;
  float* op = hout + (size_t)n * DD + hh * 16;
  const float* bp = bias + hh * 16;
  #pragma unroll
  for (int q = 0; q < 4; ++q) {
    float4 o;
    o.x = fmaf(a[q * 4 + 0], inv, bp[q * 4 + 0]);
    o.y = fmaf(a[q * 4 + 1], inv, bp[q * 4 + 1]);
    o.z = fmaf(a[q * 4 + 2], inv, bp[q * 4 + 2]);
    o.w = fmaf(a[q * 4 + 3], inv, bp[q * 4 + 3]);
    *(float4*)(op + q * 4) = o;
  }
}

// ---------------- K6: BN column stats ----------------
__global__ __launch_bounds__(256) void bnstats_kernel(
    const float* __restrict__ h, float* __restrict__ sums,
    float* __restrict__ sumsq, int N)
{
  __shared__ float rs[256], rss[256];
  const int c = threadIdx.x & 127;
  const int half = threadIdx.x >> 7;
  const int rowsPer = (N + gridDim.x - 1) / gridDim.x;
  const int r0 = blockIdx.x * rowsPer;
  const int r1 = min(N, r0 + rowsPer);
  float s = 0.f, ss = 0.f;
  for (int r = r0 + half; r < r1; r += 2) {
    float v = h[(size_t)r * DD + c];
    s += v; ss += v * v;
  }
  rs[threadIdx.x] = s; rss[threadIdx.x] = ss;
  __syncthreads();
  if (threadIdx.x < 128) {
    s = rs[threadIdx.x] + rs[threadIdx.x + 128];
    ss = rss[threadIdx.x] + rss[threadIdx.x + 128];
    atomicAdd(&sums[c], s);
    atomicAdd(&sumsq[c], ss);
  }
}

// ---------------- K7: persistent wave-specialized MFMA MLP, atomic-free ----------------
// Per tile (32 rows): GEMM1 (wave-private hidden chunk) -> private LDS -> GEMM2 K-split
// -> plain-store LDS exchange -> sum -> out. A-tile of t+NB prefetched into regs
// during tile t's GEMM2/exchange (issued after W loads so vmcnt keeps it in flight).
__global__ __launch_bounds__(256) void mlp_mfma_kernel(
    const float* __restrict__ hbuf, const float* __restrict__ sum1,
    const float* __restrict__ ss1, const float* __restrict__ bn1_g,
    const float* __restrict__ bn1_b, const _Float16* __restrict__ W1P,
    const _Float16* __restrict__ W2P, const float* __restrict__ b1,
    const float* __restrict__ b2, float* __restrict__ out, int N, int T)
{
  __shared__ char smem[40960];   // As 8KB | Htr 4x8KB ; Xch (32KB) aliases As+Htr[0..2]
  __shared__ float sc1[128], sh1[128];
  char* As = smem;
  char* Htr = smem + 8192;
  char* Xch = smem;
  const int tid = threadIdx.x;
  const int wv = tid >> 6, lane = tid & 63;
  const int l15 = lane & 15, l4 = lane >> 4;
  const int row = tid >> 3, seg = tid & 7;

  if (tid < 128) {   // fold BN1-finalize (once per block)
    float mean = sum1[tid] / (float)N;
    float var = ss1[tid] / (float)N - mean * mean;
    float sc = bn1_g[tid] * rsqrtf(var + 1e-5f);
    sc1[tid] = sc;
    sh1[tid] = bn1_b[tid] - mean * sc;
  }
  // hoisted biases
  float bb1[8];
  #pragma unroll
  for (int nf = 0; nf < 8; ++nf) bb1[nf] = b1[wv * 128 + nf * 16 + l15];
  float4 b2r[4];
  #pragma unroll
  for (int q = 0; q < 4; ++q) b2r[q] = *(const float4*)&b2[seg * 16 + q * 4];

  int t = blockIdx.x;
  float4 pre[4];
  {
    const int n = t * 32 + row;
    const bool ok = (t < T) && (n < N);
    const float4* hp = (const float4*)(hbuf + (size_t)n * DD + seg * 16);
    const float4 z = make_float4(0.f, 0.f, 0.f, 0.f);
    #pragma unroll
    for (int c = 0; c < 4; ++c) pre[c] = ok ? hp[c] : z;
  }
  __syncthreads();   // sc1/sh1 ready

  for (; t < T; t += NB) {
    const int n0 = t * 32;
    {  // stage A = f16(BN1(pre)), swizzled
      half8 h0, h1;
      #pragma unroll
      for (int c = 0; c < 4; ++c) {
        float4 v = pre[c];
        float4 sc = *(const float4*)&sc1[seg * 16 + c * 4];
        float4 sh = *(const float4*)&sh1[seg * 16 + c * 4];
        float r0 = fmaf(v.x, sc.x, sh.x), r1 = fmaf(v.y, sc.y, sh.y);
        float r2 = fmaf(v.z, sc.z, sh.z), r3 = fmaf(v.w, sc.w, sh.w);
        if (c < 2) {
          h0[c * 4 + 0] = (_Float16)r0; h0[c * 4 + 1] = (_Float16)r1;
          h0[c * 4 + 2] = (_Float16)r2; h0[c * 4 + 3] = (_Float16)r3;
        } else {
          h1[(c - 2) * 4 + 0] = (_Float16)r0; h1[(c - 2) * 4 + 1] = (_Float16)r1;
          h1[(c - 2) * 4 + 2] = (_Float16)r2; h1[(c - 2) * 4 + 3] = (_Float16)r3;
        }
      }
      *(half8*)(As + swz256(row, seg * 32)) = h0;
      *(half8*)(As + swz256(row, seg * 32 + 16)) = h1;
    }
    __syncthreads();   // B2: As ready

    half8 af[2][4];
    #pragma unroll
    for (int mf = 0; mf < 2; ++mf)
      #pragma unroll
      for (int kc = 0; kc < 4; ++kc)
        af[mf][kc] = *(const half8*)(As + swz256(mf * 16 + l15, kc * 64 + l4 * 16));

    // GEMM1 per-nf -> private LDS slice
    char* myH = Htr + wv * 8192;
    #pragma unroll
    for (int nf = 0; nf < 8; ++nf) {
      floatx4 a0 = (floatx4)0.f, a1 = (floatx4)0.f;
      #pragma unroll
      for (int kc = 0; kc < 4; ++kc) {
        half8 bf = *(const half8*)(W1P + (((size_t)kc * 512 + wv * 128 + nf * 16 + l15) * 4 + l4) * 8);
        a0 = __builtin_amdgcn_mfma_f32_16x16x32_f16(af[0][kc], bf, a0, 0, 0, 0);
        a1 = __builtin_amdgcn_mfma_f32_16x16x32_f16(af[1][kc], bf, a1, 0, 0, 0);
      }
      const float bb = bb1[nf];
      #pragma unroll
      for (int r = 0; r < 4; ++r) {
        float v0 = a0[r] + bb; v0 = v0 > 0.f ? v0 : 0.f;
        float v1 = a1[r] + bb; v1 = v1 > 0.f ? v1 : 0.f;
        *(_Float16*)(myH + swz256(l4 * 4 + r,      (nf * 16 + l15) * 2)) = (_Float16)v0;
        *(_Float16*)(myH + swz256(16 + l4 * 4 + r, (nf * 16 + l15) * 2)) = (_Float16)v1;
      }
    }

    // transpose-read own slice (in-wave lgkmcnt only)
    half8 af2[2][4];
    #pragma unroll
    for (int mf = 0; mf < 2; ++mf)
      #pragma unroll
      for (int kc = 0; kc < 4; ++kc)
        af2[mf][kc] = *(const half8*)(myH + swz256(mf * 16 + l15, kc * 64 + l4 * 16));

    // GEMM2 partial: K-chunk wv
    floatx4 acc2[2][8];
    #pragma unroll
    for (int mf = 0; mf < 2; ++mf)
      #pragma unroll
      for (int nf = 0; nf < 8; ++nf) acc2[mf][nf] = (floatx4)0.f;

    #pragma unroll
    for (int nf = 0; nf < 8; ++nf) {
      #pragma unroll
      for (int kc = 0; kc < 4; ++kc) {
        half8 bf = *(const half8*)(W2P + (((size_t)(wv * 4 + kc) * 128 + nf * 16 + l15) * 4 + l4) * 8);
        acc2[0][nf] = __builtin_amdgcn_mfma_f32_16x16x32_f16(af2[0][kc], bf, acc2[0][nf], 0, 0, 0);
        acc2[1][nf] = __builtin_amdgcn_mfma_f32_16x16x32_f16(af2[1][kc], bf, acc2[1][nf], 0, 0, 0);
      }
    }

    {  // prefetch next tile's A-rows (after W loads -> stays in flight across waits)
      const int tn = t + NB;
      const int n = tn * 32 + row;
      const bool ok = (tn < T) && (n < N);
      const float4* hp = (const float4*)(hbuf + (size_t)n * DD + seg * 16);
      const float4 z = make_float4(0.f, 0.f, 0.f, 0.f);
      #pragma unroll
      for (int c = 0; c < 4; ++c) pre[c] = ok ? hp[c] : z;
    }

    __syncthreads();   // B3: As/Htr dead -> reuse as Xch

    {  // plain-store exchange
      char* myX = Xch + wv * 8192;
      #pragma unroll
      for (int nf = 0; nf < 8; ++nf) {
        const int col2 = (nf * 16 + l15) * 2;
        #pragma unroll
        for (int mf = 0; mf < 2; ++mf) {
          #pragma unroll
          for (int r = 0; r < 4; ++r)
            *(_Float16*)(myX + swz256(mf * 16 + l4 * 4 + r, col2)) = (_Float16)acc2[mf][nf][r];
        }
      }
    }
    __syncthreads();   // B4

    {  // reduce 4 partials + b2, coalesced store
      const int n = n0 + row;
      if (n < N) {
        float accv[16];
        #pragma unroll
        for (int q = 0; q < 4; ++q) {
          accv[q * 4 + 0] = b2r[q].x; accv[q * 4 + 1] = b2r[q].y;
          accv[q * 4 + 2] = b2r[q].z; accv[q * 4 + 3] = b2r[q].w;
        }
        #pragma unroll
        for (int s = 0; s < 4; ++s) {
          half8 ha = *(const half8*)(Xch + s * 8192 + swz256(row, seg * 32));
          half8 hb = *(const half8*)(Xch + s * 8192 + swz256(row, seg * 32 + 16));
          #pragma unroll
          for (int j = 0; j < 8; ++j) {
            accv[j] += (float)ha[j];
            accv[8 + j] += (float)hb[j];
          }
        }
        #pragma unroll
        for (int q = 0; q < 4; ++q) {
          float4 v = make_float4(accv[q * 4], accv[q * 4 + 1], accv[q * 4 + 2], accv[q * 4 + 3]);
          *(float4*)&out[(size_t)n * DD + seg * 16 + q * 4] = v;
        }
      }
    }
    __syncthreads();   // B5: Xch reads done before next stage overwrites As
  }
}

// ---------------- K8: BN2 finalize + apply in one pass ----------------
__global__ __launch_bounds__(256) void applybn_kernel(
    float* __restrict__ out, const float* __restrict__ sum2,
    const float* __restrict__ ss2, const float* __restrict__ gamma,
    const float* __restrict__ beta, int N, int total4)
{
  __shared__ float sc[128], sh[128];
  if (threadIdx.x < 128) {
    int c = threadIdx.x;
    float mean = sum2[c] / (float)N;
    float var = ss2[c] / (float)N - mean * mean;
    float s = gamma[c] * rsqrtf(var + 1e-5f);
    sc[c] = s;
    sh[c] = beta[c] - mean * s;
  }
  __syncthreads();
  int i = blockIdx.x * 256 + threadIdx.x;
  const int stride = gridDim.x * 256;
  for (; i < total4; i += stride) {
    float4 v = ((float4*)out)[i];
    int c = (i & 31) * 4;
    float4 scv = *(const float4*)&sc[c];
    float4 shv = *(const float4*)&sh[c];
    v.x = fmaf(v.x, scv.x, shv.x); v.y = fmaf(v.y, scv.y, shv.y);
    v.z = fmaf(v.z, scv.z, shv.z); v.w = fmaf(v.w, scv.w, shv.w);
    ((float4*)out)[i] = v;
  }
}

extern "C" void kernel_launch(void* const* d_in, const int* in_sizes, int n_in,
                              void* d_out, int out_size, void* d_ws, size_t ws_size,
                              hipStream_t stream) {
  const float* x        = (const float*)d_in[0];
  const int*   src      = (const int*)d_in[1];
  const int*   dst      = (const int*)d_in[2];
  const float* W        = (const float*)d_in[3];
  const float* attn_l   = (const float*)d_in[4];
  const float* attn_r   = (const float*)d_in[5];
  const float* bias_gat = (const float*)d_in[6];
  const float* bn1_g    = (const float*)d_in[7];
  const float* bn1_b    = (const float*)d_in[8];
  const float* W1       = (const float*)d_in[9];
  const float* b1       = (const float*)d_in[10];
  const float* W2       = (const float*)d_in[11];
  const float* b2       = (const float*)d_in[12];
  const float* bn2_g    = (const float*)d_in[13];
  const float* bn2_b    = (const float*)d_in[14];
  float* out = (float*)d_out;

  const int N = in_sizes[0] / DD;
  const int E = in_sizes[1];
  const int NPAD = ((N + 1023) / 1024) * 1024;
  const int NCHUNK = NPAD / 1024;
  const int T = (N + 31) / 32;

  // workspace layout
  _Float16* feat16 = (_Float16*)d_ws;                 // N*128 f16 (padded to even)
  float* hbuf = (float*)(feat16 + (size_t)((N + 1) & ~1) * DD);  // N*128 f32
  float* el   = hbuf + (size_t)N * DD;                // N*8
  float* er   = el + (size_t)N * NHEAD;               // N*8
  int* counts = (int*)(er + (size_t)N * NHEAD);       // NPAD
  int* cursor = counts + NPAD;                        // NPAD
  int* offsets = cursor + NPAD;                       // NPAD
  int* srcl   = offsets + NPAD;                       // E
  int* btot   = srcl + E;                             // 64
  int* bof    = btot + 64;                            // 64
  float* stats = (float*)(bof + 64);                  // 1024 floats
  float* sum1 = stats, *ss1 = stats + 128;
  float* sum2 = stats + 256, *ss2 = stats + 384;
  _Float16* WP  = (_Float16*)(stats + 1024);          // 16384 f16
  _Float16* W1P = WP + 4 * 128 * 32;                  // 65536 f16
  _Float16* W2P = W1P + 4 * 512 * 32;                 // 65536 f16

  hipMemsetAsync(counts, 0, (size_t)2 * NPAD * sizeof(int), stream);
  hipMemsetAsync(stats, 0, 512 * sizeof(float), stream);

  pack_kernel<<<256, 256, 0, stream>>>(W, W1, W2, WP, W1P, W2P);
  feat_mfma_kernel<<<NB, 256, 0, stream>>>(x, WP, attn_l, attn_r, feat16, el, er, N, T);
  count_kernel<<<(E + 255) / 256, 256, 0, stream>>>(dst, counts, E);
  scan1_kernel<<<NCHUNK, 256, 0, stream>>>(counts, offsets, btot);
  scan2_kernel<<<1, 64, 0, stream>>>(btot, bof, NCHUNK);
  fill_kernel<<<(E + 255) / 256, 256, 0, stream>>>(src, dst, offsets, bof, cursor, srcl, E);
  agg_kernel<<<(N * NHEAD + 255) / 256, 256, 0, stream>>>(feat16, el, er, offsets, bof,
                                                          srcl, bias_gat, hbuf, N);
  bnstats_kernel<<<256, 256, 0, stream>>>(hbuf, sum1, ss1, N);
  mlp_mfma_kernel<<<NB, 256, 0, stream>>>(hbuf, sum1, ss1, bn1_g, bn1_b, W1P, W2P,
                                          b1, b2, out, N, T);
  bnstats_kernel<<<256, 256, 0, stream>>>(out, sum2, ss2, N);
  applybn_kernel<<<2048, 256, 0, stream>>>(out, sum2, ss2, bn2_g, bn2_b, N, N * DD / 4);
}